// Round 6
// baseline (5823.885 us; speedup 1.0000x reference)
//
#include <hip/hip_runtime.h>
#include <math.h>

static __device__ __forceinline__ float sigf(float v) { return 1.0f / (1.0f + expf(-v)); }

// ---------------------------------------------------------------------------
// GEMM: C[M,N] = act(A[M,K] @ B[N,K]^T + bias[N]);  act: 0=none, 1=relu, 2=tanh
// 128x64 tile, BK=16, 256 threads, 8x4 per thread.
// ---------------------------------------------------------------------------
__global__ __launch_bounds__(256) void gemm128x64(
    const float* __restrict__ A, const float* __restrict__ Bw,
    const float* __restrict__ bias, float* __restrict__ C,
    int M, int N, int K, int act)
{
  __shared__ float As[16][132];
  __shared__ float Bs[16][68];
  const int tid = threadIdx.x;
  const int tm = tid & 15, tn = tid >> 4;
  const int m0 = blockIdx.x * 128, n0 = blockIdx.y * 64;
  float acc[8][4];
#pragma unroll
  for (int i = 0; i < 8; ++i)
#pragma unroll
    for (int j = 0; j < 4; ++j) acc[i][j] = 0.f;

  for (int k0 = 0; k0 < K; k0 += 16) {
    {
      int row = tid >> 1, kc = (tid & 1) * 8;
      float4 a0 = *(const float4*)(A + (size_t)(m0 + row) * K + k0 + kc);
      float4 a1 = *(const float4*)(A + (size_t)(m0 + row) * K + k0 + kc + 4);
      As[kc + 0][row] = a0.x; As[kc + 1][row] = a0.y;
      As[kc + 2][row] = a0.z; As[kc + 3][row] = a0.w;
      As[kc + 4][row] = a1.x; As[kc + 5][row] = a1.y;
      As[kc + 6][row] = a1.z; As[kc + 7][row] = a1.w;
      int brow = tid >> 2, bkc = (tid & 3) * 4;
      float4 b0 = *(const float4*)(Bw + (size_t)(n0 + brow) * K + k0 + bkc);
      Bs[bkc + 0][brow] = b0.x; Bs[bkc + 1][brow] = b0.y;
      Bs[bkc + 2][brow] = b0.z; Bs[bkc + 3][brow] = b0.w;
    }
    __syncthreads();
#pragma unroll
    for (int k = 0; k < 16; ++k) {
      float av[8], bv[4];
      *(float4*)(av)     = *(const float4*)&As[k][tm * 8];
      *(float4*)(av + 4) = *(const float4*)&As[k][tm * 8 + 4];
      *(float4*)(bv)     = *(const float4*)&Bs[k][tn * 4];
#pragma unroll
      for (int i = 0; i < 8; ++i)
#pragma unroll
        for (int j = 0; j < 4; ++j) acc[i][j] = fmaf(av[i], bv[j], acc[i][j]);
    }
    __syncthreads();
  }
#pragma unroll
  for (int i = 0; i < 8; ++i) {
    int row = m0 + tm * 8 + i;
    float o[4];
#pragma unroll
    for (int j = 0; j < 4; ++j) {
      float v = acc[i][j] + bias[n0 + tn * 4 + j];
      if (act == 1) v = fmaxf(v, 0.f);
      else if (act == 2) v = tanhf(v);
      o[j] = v;
    }
    *(float4*)(C + (size_t)row * N + n0 + tn * 4) = *(float4*)o;
  }
}

// ---------------------------------------------------------------------------
// 64x64 tile GEMM (same contract).
// ---------------------------------------------------------------------------
__global__ __launch_bounds__(256) void gemm64(
    const float* __restrict__ A, const float* __restrict__ Bw,
    const float* __restrict__ bias, float* __restrict__ C,
    int M, int N, int K, int act)
{
  __shared__ float As[16][68];
  __shared__ float Bs[16][68];
  const int tid = threadIdx.x;
  const int tm = tid & 15, tn = tid >> 4;
  const int m0 = blockIdx.x * 64, n0 = blockIdx.y * 64;
  float acc[4][4];
#pragma unroll
  for (int i = 0; i < 4; ++i)
#pragma unroll
    for (int j = 0; j < 4; ++j) acc[i][j] = 0.f;

  for (int k0 = 0; k0 < K; k0 += 16) {
    {
      int row = tid >> 2, kc = (tid & 3) << 2;
      float4 a = *(const float4*)(A + (size_t)(m0 + row) * K + k0 + kc);
      As[kc + 0][row] = a.x; As[kc + 1][row] = a.y;
      As[kc + 2][row] = a.z; As[kc + 3][row] = a.w;
      float4 b = *(const float4*)(Bw + (size_t)(n0 + row) * K + k0 + kc);
      Bs[kc + 0][row] = b.x; Bs[kc + 1][row] = b.y;
      Bs[kc + 2][row] = b.z; Bs[kc + 3][row] = b.w;
    }
    __syncthreads();
#pragma unroll
    for (int k = 0; k < 16; ++k) {
      float av[4], bv[4];
      *(float4*)(av) = *(const float4*)&As[k][tm * 4];
      *(float4*)(bv) = *(const float4*)&Bs[k][tn * 4];
#pragma unroll
      for (int i = 0; i < 4; ++i)
#pragma unroll
        for (int j = 0; j < 4; ++j) acc[i][j] = fmaf(av[i], bv[j], acc[i][j]);
    }
    __syncthreads();
  }
#pragma unroll
  for (int i = 0; i < 4; ++i) {
    int row = m0 + tm * 4 + i;
    float o[4];
#pragma unroll
    for (int j = 0; j < 4; ++j) {
      float v = acc[i][j] + bias[n0 + tn * 4 + j];
      if (act == 1) v = fmaxf(v, 0.f);
      else if (act == 2) v = tanhf(v);
      o[j] = v;
    }
    *(float4*)(C + (size_t)row * N + n0 + tn * 4) = *(float4*)o;
  }
}

// ---------------------------------------------------------------------------
// Pack LSTM weights: wP[j][k][s] = w[(s*256+j)*256 + k] (s = i,f,g,o);
// bP[j][s] = bih[s*256+j] + bhh[s*256+j].  grid 256 (j), block 256 (k).
// ---------------------------------------------------------------------------
__global__ __launch_bounds__(256) void prep_pack(
    const float* __restrict__ wih, const float* __restrict__ whh,
    const float* __restrict__ bih, const float* __restrict__ bhh,
    float* __restrict__ wihP, float* __restrict__ whhP, float* __restrict__ bP)
{
  const int j = blockIdx.x, k = threadIdx.x;
  float4 a, c;
  a.x = wih[(0 * 256 + j) * 256 + k];
  a.y = wih[(1 * 256 + j) * 256 + k];
  a.z = wih[(2 * 256 + j) * 256 + k];
  a.w = wih[(3 * 256 + j) * 256 + k];
  *(float4*)&wihP[((size_t)j * 256 + k) * 4] = a;
  c.x = whh[(0 * 256 + j) * 256 + k];
  c.y = whh[(1 * 256 + j) * 256 + k];
  c.z = whh[(2 * 256 + j) * 256 + k];
  c.w = whh[(3 * 256 + j) * 256 + k];
  *(float4*)&whhP[((size_t)j * 256 + k) * 4] = c;
  if (k < 4) bP[j * 4 + k] = bih[k * 256 + j] + bhh[k * 256 + j];
}

// ---------------------------------------------------------------------------
// Per-slab 256x256 transpose: out[t][c][r] = in[t][r][c]. grid (T, 64), 256 thr.
// ---------------------------------------------------------------------------
__global__ __launch_bounds__(256) void transpose256(
    const float* __restrict__ in, float* __restrict__ out)
{
  const int t = blockIdx.x, c4 = blockIdx.y;
  const int r = threadIdx.x;
  float4 v = *(const float4*)(in + ((size_t)t * 256 + r) * 256 + c4 * 4);
  float* op = out + (size_t)t * 65536 + (size_t)(c4 * 4) * 256 + r;
  op[0]   = v.x;
  op[256] = v.y;
  op[512] = v.z;
  op[768] = v.w;
}

// ---------------------------------------------------------------------------
// Persistent LSTM sequence kernel: all 90 cells in one launch.
// Grid 256 = 32 jg x 8 bg (1 block/CU, all co-resident). Thread = 8 ji x 32 bi.
// Each block: 8-j weight slice (64 KB), 32-b h/x slice (2x32 KB) per cell.
// Device-scope grid barrier between cells (89 total).
// ---------------------------------------------------------------------------
__device__ __forceinline__ void grid_barrier(int* cnt, int target) {
  __syncthreads();
  if (threadIdx.x == 0) {
    __threadfence();  // release: make this block's h/c stores agent-visible
    __hip_atomic_fetch_add(cnt, 1, __ATOMIC_ACQ_REL, __HIP_MEMORY_SCOPE_AGENT);
    while (__hip_atomic_load(cnt, __ATOMIC_ACQUIRE, __HIP_MEMORY_SCOPE_AGENT) < target) {
      __builtin_amdgcn_s_sleep(1);
    }
  }
  __syncthreads();
  __threadfence();  // acquire: invalidate stale L1/L2 before reading peers' h
}

template <bool HASX>
__device__ __forceinline__ void cell_compute(
    const float* __restrict__ xT,
    const float* __restrict__ wihP, const float* __restrict__ whhP,
    const float* __restrict__ bP,
    const float* __restrict__ hin, float* __restrict__ cbuf,
    float* __restrict__ hout, float* __restrict__ hcopy,
    int j, int b)
{
  const float4* wh = (const float4*)(whhP + (size_t)j * 1024);
  const float4* wi = (const float4*)(wihP + (size_t)j * 1024);
  float4 acc = *(const float4*)(bP + j * 4);
#pragma unroll 8
  for (int k = 0; k < 256; ++k) {
    const float hv = hin[k * 256 + b];
    const float4 w = wh[k];
    acc.x = fmaf(hv, w.x, acc.x);
    acc.y = fmaf(hv, w.y, acc.y);
    acc.z = fmaf(hv, w.z, acc.z);
    acc.w = fmaf(hv, w.w, acc.w);
    if (HASX) {
      const float xv = xT[k * 256 + b];
      const float4 v = wi[k];
      acc.x = fmaf(xv, v.x, acc.x);
      acc.y = fmaf(xv, v.y, acc.y);
      acc.z = fmaf(xv, v.z, acc.z);
      acc.w = fmaf(xv, v.w, acc.w);
    }
  }
  const int idx = j * 256 + b;
  const float cold = cbuf[idx];
  const float ig = sigf(acc.x), fg = sigf(acc.y);
  const float gg = tanhf(acc.z), og = sigf(acc.w);
  const float cn = fg * cold + ig * gg;
  const float hn = og * tanhf(cn);
  cbuf[idx] = cn;
  hout[idx] = hn;
  if (hcopy) hcopy[idx] = hn;
}

__global__ __launch_bounds__(256, 1) void lstm_seq(
    const float* __restrict__ z2T,   // [20][256][256] (k,b)
    const float* __restrict__ wihP,  // [6][256][256][4]
    const float* __restrict__ whhP,
    const float* __restrict__ bP,    // [6][256][4]
    float* __restrict__ hb,          // 12 x 65536 (6 layers x ping-pong)
    float* __restrict__ cb,          // 6 x 65536
    float* __restrict__ H3T,         // [10][256][256] (j,b)
    int* __restrict__ cnt)
{
  const int jg = blockIdx.x >> 3, bg = blockIdx.x & 7;
  const int ji = threadIdx.x >> 5, bi = threadIdx.x & 31;
  const int j = jg * 8 + ji;
  const int b = bg * 32 + bi;

  auto HBuf = [&](int l, int p) { return hb + (size_t)(l * 2 + p) * 65536; };
  auto CBuf = [&](int l) { return cb + (size_t)l * 65536; };

  int pp[6] = {0, 0, 0, 0, 0, 0};
  int phase = 0;

  // encoder: 20 steps x (en1, en2, en3)
  for (int t = 0; t < 20; ++t) {
    cell_compute<true>(z2T + (size_t)t * 65536,
                       wihP + 0 * 262144, whhP + 0 * 262144, bP + 0 * 1024,
                       HBuf(0, pp[0]), CBuf(0), HBuf(0, pp[0] ^ 1), nullptr, j, b);
    pp[0] ^= 1; grid_barrier(cnt, (++phase) * 256);
    cell_compute<true>(HBuf(0, pp[0]),
                       wihP + 1 * 262144, whhP + 1 * 262144, bP + 1 * 1024,
                       HBuf(1, pp[1]), CBuf(1), HBuf(1, pp[1] ^ 1), nullptr, j, b);
    pp[1] ^= 1; grid_barrier(cnt, (++phase) * 256);
    cell_compute<true>(HBuf(1, pp[1]),
                       wihP + 2 * 262144, whhP + 2 * 262144, bP + 2 * 1024,
                       HBuf(2, pp[2]), CBuf(2), HBuf(2, pp[2] ^ 1), nullptr, j, b);
    pp[2] ^= 1; grid_barrier(cnt, (++phase) * 256);
  }
  // decoder: 10 steps x (de1 [x=0], de2, de3)
  for (int s = 0; s < 10; ++s) {
    const float* h1in = (s == 0) ? HBuf(2, pp[2]) : HBuf(3, pp[3]);
    cell_compute<false>(nullptr,
                        whhP + 3 * 262144, whhP + 3 * 262144, bP + 3 * 1024,
                        h1in, CBuf(3), HBuf(3, pp[3] ^ 1), nullptr, j, b);
    pp[3] ^= 1; grid_barrier(cnt, (++phase) * 256);
    cell_compute<true>(HBuf(3, pp[3]),
                       wihP + 4 * 262144, whhP + 4 * 262144, bP + 4 * 1024,
                       HBuf(4, pp[4]), CBuf(4), HBuf(4, pp[4] ^ 1), nullptr, j, b);
    pp[4] ^= 1; grid_barrier(cnt, (++phase) * 256);
    cell_compute<true>(HBuf(4, pp[4]),
                       wihP + 5 * 262144, whhP + 5 * 262144, bP + 5 * 1024,
                       HBuf(5, pp[5]), CBuf(5), HBuf(5, pp[5] ^ 1),
                       H3T + (size_t)s * 65536, j, b);
    pp[5] ^= 1;
    if (s < 9) grid_barrier(cnt, (++phase) * 256);
  }
}

// ---------------------------------------------------------------------------

extern "C" void kernel_launch(void* const* d_in, const int* in_sizes, int n_in,
                              void* d_out, int out_size, void* d_ws, size_t ws_size,
                              hipStream_t stream)
{
  const float* x_in  = (const float*)d_in[0];
  const float* w_en1 = (const float*)d_in[1];
  const float* b_en1 = (const float*)d_in[2];
  const float* w_en2 = (const float*)d_in[3];
  const float* b_en2 = (const float*)d_in[4];
  const float* cw[6][4];
  for (int i = 0; i < 6; ++i)
    for (int j = 0; j < 4; ++j) cw[i][j] = (const float*)d_in[5 + i * 4 + j];
  const float* w_de1 = (const float*)d_in[29];
  const float* b_de1 = (const float*)d_in[30];
  const float* w_de2 = (const float*)d_in[31];
  const float* b_de2 = (const float*)d_in[32];
  float* out = (float*)d_out;

  // ---- workspace layout (floats) ----
  float* ws   = (float*)d_ws;
  float* wihP = ws;                        // 6 * 262144
  float* whhP = wihP + 6 * 262144;         // 6 * 262144
  float* bP   = whhP + 6 * 262144;         // 6 * 1024
  float* st   = bP + 6 * 1024;             // hb 12*65536 + cb 6*65536 + cnt
  float* hb   = st;
  float* cb   = st + 12 * 65536;
  int*   cnt  = (int*)(st + 18 * 65536);   // 16-float pad region
  float* H3T  = st + 18 * 65536 + 16;      // 10 * 65536
  float* R1   = H3T + 10 * 65536;          // 5,242,880: z1 -> z2T | (H3std, y1)
  float* R2   = R1 + 5242880;              // 1,310,720: z2

  // ---- weight packing + zero states/counter (every call) ----
  for (int i = 0; i < 6; ++i)
    prep_pack<<<256, 256, 0, stream>>>(cw[i][0], cw[i][1], cw[i][2], cw[i][3],
                                       wihP + i * 262144, whhP + i * 262144,
                                       bP + i * 1024);
  hipMemsetAsync(st, 0, (size_t)(18 * 65536 + 16) * sizeof(float), stream);

  // ---- batched encoder feedforward ----
  float* z1  = R1;
  float* z2  = R2;
  float* z2T = R1;  // z1 dead after fc_en2
  gemm128x64<<<dim3(5120 / 128, 1024 / 64), 256, 0, stream>>>(
      x_in, w_en1, b_en1, z1, 5120, 1024, 4096, 1);
  gemm64<<<dim3(5120 / 64, 256 / 64), 256, 0, stream>>>(
      z1, w_en2, b_en2, z2, 5120, 256, 1024, 1);
  transpose256<<<dim3(20, 64), 256, 0, stream>>>(z2, z2T);  // [t][b][k]->[t][k][b]

  // ---- entire recurrence in one persistent kernel ----
  lstm_seq<<<256, 256, 0, stream>>>(z2T, wihP, whhP, bP, hb, cb, H3T, cnt);

  // ---- batched decoder output FCs ----
  float* H3std = R1;             // [s*256+b][j]
  float* y1    = R1 + 1310720;   // 2560 x 1024
  transpose256<<<dim3(10, 64), 256, 0, stream>>>(H3T, H3std);  // [s][j][b]->[s][b][j]
  gemm64<<<dim3(2560 / 64, 1024 / 64), 256, 0, stream>>>(
      H3std, w_de1, b_de1, y1, 2560, 1024, 256, 1);
  gemm128x64<<<dim3(2560 / 128, 4096 / 64), 256, 0, stream>>>(
      y1, w_de2, b_de2, out, 2560, 4096, 1024, 2);

  (void)in_sizes; (void)n_in; (void)out_size; (void)ws_size;
}

// Round 7
// 2680.857 us; speedup vs baseline: 2.1724x; 2.1724x over previous
//
#include <hip/hip_runtime.h>
#include <math.h>

static __device__ __forceinline__ float sigf(float v) { return 1.0f / (1.0f + expf(-v)); }

// ---------------------------------------------------------------------------
// GEMM: C[M,N] = act(A[M,K] @ B[N,K]^T + bias[N]);  act: 0=none, 1=relu, 2=tanh
// 128x64 tile, BK=16, 256 threads, 8x4 per thread.
// ---------------------------------------------------------------------------
__global__ __launch_bounds__(256) void gemm128x64(
    const float* __restrict__ A, const float* __restrict__ Bw,
    const float* __restrict__ bias, float* __restrict__ C,
    int M, int N, int K, int act)
{
  __shared__ float As[16][132];
  __shared__ float Bs[16][68];
  const int tid = threadIdx.x;
  const int tm = tid & 15, tn = tid >> 4;
  const int m0 = blockIdx.x * 128, n0 = blockIdx.y * 64;
  float acc[8][4];
#pragma unroll
  for (int i = 0; i < 8; ++i)
#pragma unroll
    for (int j = 0; j < 4; ++j) acc[i][j] = 0.f;

  for (int k0 = 0; k0 < K; k0 += 16) {
    {
      int row = tid >> 1, kc = (tid & 1) * 8;
      float4 a0 = *(const float4*)(A + (size_t)(m0 + row) * K + k0 + kc);
      float4 a1 = *(const float4*)(A + (size_t)(m0 + row) * K + k0 + kc + 4);
      As[kc + 0][row] = a0.x; As[kc + 1][row] = a0.y;
      As[kc + 2][row] = a0.z; As[kc + 3][row] = a0.w;
      As[kc + 4][row] = a1.x; As[kc + 5][row] = a1.y;
      As[kc + 6][row] = a1.z; As[kc + 7][row] = a1.w;
      int brow = tid >> 2, bkc = (tid & 3) * 4;
      float4 b0 = *(const float4*)(Bw + (size_t)(n0 + brow) * K + k0 + bkc);
      Bs[bkc + 0][brow] = b0.x; Bs[bkc + 1][brow] = b0.y;
      Bs[bkc + 2][brow] = b0.z; Bs[bkc + 3][brow] = b0.w;
    }
    __syncthreads();
#pragma unroll
    for (int k = 0; k < 16; ++k) {
      float av[8], bv[4];
      *(float4*)(av)     = *(const float4*)&As[k][tm * 8];
      *(float4*)(av + 4) = *(const float4*)&As[k][tm * 8 + 4];
      *(float4*)(bv)     = *(const float4*)&Bs[k][tn * 4];
#pragma unroll
      for (int i = 0; i < 8; ++i)
#pragma unroll
        for (int j = 0; j < 4; ++j) acc[i][j] = fmaf(av[i], bv[j], acc[i][j]);
    }
    __syncthreads();
  }
#pragma unroll
  for (int i = 0; i < 8; ++i) {
    int row = m0 + tm * 8 + i;
    float o[4];
#pragma unroll
    for (int j = 0; j < 4; ++j) {
      float v = acc[i][j] + bias[n0 + tn * 4 + j];
      if (act == 1) v = fmaxf(v, 0.f);
      else if (act == 2) v = tanhf(v);
      o[j] = v;
    }
    *(float4*)(C + (size_t)row * N + n0 + tn * 4) = *(float4*)o;
  }
}

// ---------------------------------------------------------------------------
// 64x64 tile GEMM (same contract).
// ---------------------------------------------------------------------------
__global__ __launch_bounds__(256) void gemm64(
    const float* __restrict__ A, const float* __restrict__ Bw,
    const float* __restrict__ bias, float* __restrict__ C,
    int M, int N, int K, int act)
{
  __shared__ float As[16][68];
  __shared__ float Bs[16][68];
  const int tid = threadIdx.x;
  const int tm = tid & 15, tn = tid >> 4;
  const int m0 = blockIdx.x * 64, n0 = blockIdx.y * 64;
  float acc[4][4];
#pragma unroll
  for (int i = 0; i < 4; ++i)
#pragma unroll
    for (int j = 0; j < 4; ++j) acc[i][j] = 0.f;

  for (int k0 = 0; k0 < K; k0 += 16) {
    {
      int row = tid >> 2, kc = (tid & 3) << 2;
      float4 a = *(const float4*)(A + (size_t)(m0 + row) * K + k0 + kc);
      As[kc + 0][row] = a.x; As[kc + 1][row] = a.y;
      As[kc + 2][row] = a.z; As[kc + 3][row] = a.w;
      float4 b = *(const float4*)(Bw + (size_t)(n0 + row) * K + k0 + kc);
      Bs[kc + 0][row] = b.x; Bs[kc + 1][row] = b.y;
      Bs[kc + 2][row] = b.z; Bs[kc + 3][row] = b.w;
    }
    __syncthreads();
#pragma unroll
    for (int k = 0; k < 16; ++k) {
      float av[4], bv[4];
      *(float4*)(av) = *(const float4*)&As[k][tm * 4];
      *(float4*)(bv) = *(const float4*)&Bs[k][tn * 4];
#pragma unroll
      for (int i = 0; i < 4; ++i)
#pragma unroll
        for (int j = 0; j < 4; ++j) acc[i][j] = fmaf(av[i], bv[j], acc[i][j]);
    }
    __syncthreads();
  }
#pragma unroll
  for (int i = 0; i < 4; ++i) {
    int row = m0 + tm * 4 + i;
    float o[4];
#pragma unroll
    for (int j = 0; j < 4; ++j) {
      float v = acc[i][j] + bias[n0 + tn * 4 + j];
      if (act == 1) v = fmaxf(v, 0.f);
      else if (act == 2) v = tanhf(v);
      o[j] = v;
    }
    *(float4*)(C + (size_t)row * N + n0 + tn * 4) = *(float4*)o;
  }
}

// ---------------------------------------------------------------------------
// Pack LSTM weights: wP[j][k][s] = w[(s*256+j)*256 + k] (s = i,f,g,o);
// bP[j][s] = bih[s*256+j] + bhh[s*256+j].  grid 256 (j), block 256 (k).
// ---------------------------------------------------------------------------
__global__ __launch_bounds__(256) void prep_pack(
    const float* __restrict__ wih, const float* __restrict__ whh,
    const float* __restrict__ bih, const float* __restrict__ bhh,
    float* __restrict__ wihP, float* __restrict__ whhP, float* __restrict__ bP)
{
  const int j = blockIdx.x, k = threadIdx.x;
  float4 a, c;
  a.x = wih[(0 * 256 + j) * 256 + k];
  a.y = wih[(1 * 256 + j) * 256 + k];
  a.z = wih[(2 * 256 + j) * 256 + k];
  a.w = wih[(3 * 256 + j) * 256 + k];
  *(float4*)&wihP[((size_t)j * 256 + k) * 4] = a;
  c.x = whh[(0 * 256 + j) * 256 + k];
  c.y = whh[(1 * 256 + j) * 256 + k];
  c.z = whh[(2 * 256 + j) * 256 + k];
  c.w = whh[(3 * 256 + j) * 256 + k];
  *(float4*)&whhP[((size_t)j * 256 + k) * 4] = c;
  if (k < 4) bP[j * 4 + k] = bih[k * 256 + j] + bhh[k * 256 + j];
}

// ---------------------------------------------------------------------------
// Per-slab 256x256 transpose: out[t][c][r] = in[t][r][c]. grid (T, 64), 256 thr.
// ---------------------------------------------------------------------------
__global__ __launch_bounds__(256) void transpose256(
    const float* __restrict__ in, float* __restrict__ out)
{
  const int t = blockIdx.x, c4 = blockIdx.y;
  const int r = threadIdx.x;
  float4 v = *(const float4*)(in + ((size_t)t * 256 + r) * 256 + c4 * 4);
  float* op = out + (size_t)t * 65536 + (size_t)(c4 * 4) * 256 + r;
  op[0]   = v.x;
  op[256] = v.y;
  op[512] = v.z;
  op[768] = v.w;
}

// ---------------------------------------------------------------------------
// LSTM cell, per-launch, LDS-staged. Grid 256 = bg(8)-major x jg(32):
// blockIdx = bg*32 + jg  (same-jg weight-sharers land on one XCD via %8).
// Block: 256 thr = 8 ji x 32 bi; thread owns (j = jg*8+ji, b = bg*32+bi).
// Stages h (and x) 32-b slices into LDS; weights stream 8-j slice from L2.
// c is in-place (thread-matched). h tensors in [k][b] layout.
// ---------------------------------------------------------------------------
template <int HASX>
__global__ __launch_bounds__(256) void lstm_cell2(
    const float* __restrict__ xT,     // [256][256] (k,b)
    const float* __restrict__ wihP,   // [j][256][4]
    const float* __restrict__ whhP,   // [j][256][4]
    const float* __restrict__ bP,     // [j][4]
    const float* __restrict__ hT_in,  // [256][256] (k,b)
    float* __restrict__ cbuf,         // [256][256] (j,b), in-place
    float* __restrict__ hT_out,       // [256][256] (j,b)
    float* __restrict__ hT_copy)      // optional
{
  __shared__ float hs[256][32];
  __shared__ float xs[256][32];
  const int jg = blockIdx.x & 31, bg = blockIdx.x >> 5;
  const int ji = threadIdx.x >> 5, bi = threadIdx.x & 31;
  const int b0 = bg * 32;

#pragma unroll
  for (int k0 = 0; k0 < 256; k0 += 8) {
    hs[k0 + ji][bi] = hT_in[(k0 + ji) * 256 + b0 + bi];
    if (HASX) xs[k0 + ji][bi] = xT[(k0 + ji) * 256 + b0 + bi];
  }
  __syncthreads();

  const int j = jg * 8 + ji;
  const float4* wh = (const float4*)(whhP + (size_t)j * 1024);
  const float4* wi = (const float4*)(wihP + (size_t)j * 1024);
  float4 acc = *(const float4*)(bP + j * 4);

#pragma unroll 8
  for (int k = 0; k < 256; ++k) {
    const float hv = hs[k][bi];
    const float4 w = wh[k];
    acc.x = fmaf(hv, w.x, acc.x);
    acc.y = fmaf(hv, w.y, acc.y);
    acc.z = fmaf(hv, w.z, acc.z);
    acc.w = fmaf(hv, w.w, acc.w);
    if (HASX) {
      const float xv = xs[k][bi];
      const float4 v = wi[k];
      acc.x = fmaf(xv, v.x, acc.x);
      acc.y = fmaf(xv, v.y, acc.y);
      acc.z = fmaf(xv, v.z, acc.z);
      acc.w = fmaf(xv, v.w, acc.w);
    }
  }

  const int idx = j * 256 + b0 + bi;
  const float cold = cbuf[idx];
  const float ig = sigf(acc.x), fg = sigf(acc.y);
  const float gg = tanhf(acc.z), og = sigf(acc.w);
  const float cn = fg * cold + ig * gg;
  const float hn = og * tanhf(cn);
  cbuf[idx] = cn;
  hT_out[idx] = hn;
  if (hT_copy) hT_copy[idx] = hn;
}

// ---------------------------------------------------------------------------

extern "C" void kernel_launch(void* const* d_in, const int* in_sizes, int n_in,
                              void* d_out, int out_size, void* d_ws, size_t ws_size,
                              hipStream_t stream)
{
  const float* x_in  = (const float*)d_in[0];
  const float* w_en1 = (const float*)d_in[1];
  const float* b_en1 = (const float*)d_in[2];
  const float* w_en2 = (const float*)d_in[3];
  const float* b_en2 = (const float*)d_in[4];
  const float* cw[6][4];
  for (int i = 0; i < 6; ++i)
    for (int j = 0; j < 4; ++j) cw[i][j] = (const float*)d_in[5 + i * 4 + j];
  const float* w_de1 = (const float*)d_in[29];
  const float* b_de1 = (const float*)d_in[30];
  const float* w_de2 = (const float*)d_in[31];
  const float* b_de2 = (const float*)d_in[32];
  float* out = (float*)d_out;

  // ---- workspace layout (floats) ----
  float* ws   = (float*)d_ws;
  float* wihP = ws;                        // 6 * 262144
  float* whhP = wihP + 6 * 262144;         // 6 * 262144
  float* bP   = whhP + 6 * 262144;         // 6 * 1024
  float* hb   = bP + 6 * 1024;             // 12 * 65536 (6 layers x ping-pong)
  float* cb   = hb + 12 * 65536;           // 6 * 65536
  float* H3T  = cb + 6 * 65536;            // 10 * 65536
  float* R1   = H3T + 10 * 65536;          // 5,242,880: z1 -> z2T | (H3std, y1)
  float* R2   = R1 + 5242880;              // 1,310,720: z2

  // ---- weight packing + zero states (every call) ----
  for (int i = 0; i < 6; ++i)
    prep_pack<<<256, 256, 0, stream>>>(cw[i][0], cw[i][1], cw[i][2], cw[i][3],
                                       wihP + i * 262144, whhP + i * 262144,
                                       bP + i * 1024);
  hipMemsetAsync(hb, 0, (size_t)18 * 65536 * sizeof(float), stream);

  // ---- batched encoder feedforward ----
  float* z1  = R1;
  float* z2  = R2;
  float* z2T = R1;  // z1 dead after fc_en2
  gemm64<<<dim3(5120 / 64, 1024 / 64), 256, 0, stream>>>(
      x_in, w_en1, b_en1, z1, 5120, 1024, 4096, 1);
  gemm64<<<dim3(5120 / 64, 256 / 64), 256, 0, stream>>>(
      z1, w_en2, b_en2, z2, 5120, 256, 1024, 1);
  transpose256<<<dim3(20, 64), 256, 0, stream>>>(z2, z2T);  // [t][b][k]->[t][k][b]

  // ---- recurrence: 90 cell launches ----
  int pp[6] = {0, 0, 0, 0, 0, 0};
  auto HBuf = [&](int l, int p) { return hb + (size_t)(l * 2 + p) * 65536; };
  auto CBuf = [&](int l) { return cb + (size_t)l * 65536; };

  auto cellX = [&](const float* xT, int l, float* copy) {
    lstm_cell2<1><<<256, 256, 0, stream>>>(
        xT, wihP + l * 262144, whhP + l * 262144, bP + l * 1024,
        HBuf(l, pp[l]), CBuf(l), HBuf(l, pp[l] ^ 1), copy);
    pp[l] ^= 1;
  };

  for (int t = 0; t < 20; ++t) {
    cellX(z2T + (size_t)t * 65536, 0, nullptr);
    cellX(HBuf(0, pp[0]), 1, nullptr);
    cellX(HBuf(1, pp[1]), 2, nullptr);
  }
  for (int s = 0; s < 10; ++s) {
    const float* h1in = (s == 0) ? HBuf(2, pp[2]) : HBuf(3, pp[3]);
    lstm_cell2<0><<<256, 256, 0, stream>>>(
        nullptr, wihP + 3 * 262144, whhP + 3 * 262144, bP + 3 * 1024,
        h1in, CBuf(3), HBuf(3, pp[3] ^ 1), nullptr);
    pp[3] ^= 1;
    cellX(HBuf(3, pp[3]), 4, nullptr);
    cellX(HBuf(4, pp[4]), 5, H3T + (size_t)s * 65536);
  }

  // ---- batched decoder output FCs ----
  float* H3std = R1;             // [s*256+b][j]
  float* y1    = R1 + 1310720;   // 2560 x 1024
  transpose256<<<dim3(10, 64), 256, 0, stream>>>(H3T, H3std);  // [s][j][b]->[s][b][j]
  gemm64<<<dim3(2560 / 64, 1024 / 64), 256, 0, stream>>>(
      H3std, w_de1, b_de1, y1, 2560, 1024, 256, 1);
  gemm128x64<<<dim3(2560 / 128, 4096 / 64), 256, 0, stream>>>(
      y1, w_de2, b_de2, out, 2560, 4096, 1024, 2);

  (void)in_sizes; (void)n_in; (void)out_size; (void)ws_size;
}

// Round 8
// 2094.211 us; speedup vs baseline: 2.7809x; 1.2801x over previous
//
#include <hip/hip_runtime.h>
#include <math.h>

static __device__ __forceinline__ float sigf(float v) { return 1.0f / (1.0f + expf(-v)); }

// ---------------------------------------------------------------------------
// GEMM: C[M,N] = act(A[M,K] @ B[N,K]^T + bias[N]);  act: 0=none, 1=relu, 2=tanh
// 128x64 tile, BK=16, 256 threads, 8x4 per thread.
// ---------------------------------------------------------------------------
__global__ __launch_bounds__(256) void gemm128x64(
    const float* __restrict__ A, const float* __restrict__ Bw,
    const float* __restrict__ bias, float* __restrict__ C,
    int M, int N, int K, int act)
{
  __shared__ float As[16][132];
  __shared__ float Bs[16][68];
  const int tid = threadIdx.x;
  const int tm = tid & 15, tn = tid >> 4;
  const int m0 = blockIdx.x * 128, n0 = blockIdx.y * 64;
  float acc[8][4];
#pragma unroll
  for (int i = 0; i < 8; ++i)
#pragma unroll
    for (int j = 0; j < 4; ++j) acc[i][j] = 0.f;

  for (int k0 = 0; k0 < K; k0 += 16) {
    {
      int row = tid >> 1, kc = (tid & 1) * 8;
      float4 a0 = *(const float4*)(A + (size_t)(m0 + row) * K + k0 + kc);
      float4 a1 = *(const float4*)(A + (size_t)(m0 + row) * K + k0 + kc + 4);
      As[kc + 0][row] = a0.x; As[kc + 1][row] = a0.y;
      As[kc + 2][row] = a0.z; As[kc + 3][row] = a0.w;
      As[kc + 4][row] = a1.x; As[kc + 5][row] = a1.y;
      As[kc + 6][row] = a1.z; As[kc + 7][row] = a1.w;
      int brow = tid >> 2, bkc = (tid & 3) * 4;
      float4 b0 = *(const float4*)(Bw + (size_t)(n0 + brow) * K + k0 + bkc);
      Bs[bkc + 0][brow] = b0.x; Bs[bkc + 1][brow] = b0.y;
      Bs[bkc + 2][brow] = b0.z; Bs[bkc + 3][brow] = b0.w;
    }
    __syncthreads();
#pragma unroll
    for (int k = 0; k < 16; ++k) {
      float av[8], bv[4];
      *(float4*)(av)     = *(const float4*)&As[k][tm * 8];
      *(float4*)(av + 4) = *(const float4*)&As[k][tm * 8 + 4];
      *(float4*)(bv)     = *(const float4*)&Bs[k][tn * 4];
#pragma unroll
      for (int i = 0; i < 8; ++i)
#pragma unroll
        for (int j = 0; j < 4; ++j) acc[i][j] = fmaf(av[i], bv[j], acc[i][j]);
    }
    __syncthreads();
  }
#pragma unroll
  for (int i = 0; i < 8; ++i) {
    int row = m0 + tm * 8 + i;
    float o[4];
#pragma unroll
    for (int j = 0; j < 4; ++j) {
      float v = acc[i][j] + bias[n0 + tn * 4 + j];
      if (act == 1) v = fmaxf(v, 0.f);
      else if (act == 2) v = tanhf(v);
      o[j] = v;
    }
    *(float4*)(C + (size_t)row * N + n0 + tn * 4) = *(float4*)o;
  }
}

// ---------------------------------------------------------------------------
// 64x64 tile GEMM (same contract).
// ---------------------------------------------------------------------------
__global__ __launch_bounds__(256) void gemm64(
    const float* __restrict__ A, const float* __restrict__ Bw,
    const float* __restrict__ bias, float* __restrict__ C,
    int M, int N, int K, int act)
{
  __shared__ float As[16][68];
  __shared__ float Bs[16][68];
  const int tid = threadIdx.x;
  const int tm = tid & 15, tn = tid >> 4;
  const int m0 = blockIdx.x * 64, n0 = blockIdx.y * 64;
  float acc[4][4];
#pragma unroll
  for (int i = 0; i < 4; ++i)
#pragma unroll
    for (int j = 0; j < 4; ++j) acc[i][j] = 0.f;

  for (int k0 = 0; k0 < K; k0 += 16) {
    {
      int row = tid >> 2, kc = (tid & 3) << 2;
      float4 a = *(const float4*)(A + (size_t)(m0 + row) * K + k0 + kc);
      As[kc + 0][row] = a.x; As[kc + 1][row] = a.y;
      As[kc + 2][row] = a.z; As[kc + 3][row] = a.w;
      float4 b = *(const float4*)(Bw + (size_t)(n0 + row) * K + k0 + kc);
      Bs[kc + 0][row] = b.x; Bs[kc + 1][row] = b.y;
      Bs[kc + 2][row] = b.z; Bs[kc + 3][row] = b.w;
    }
    __syncthreads();
#pragma unroll
    for (int k = 0; k < 16; ++k) {
      float av[4], bv[4];
      *(float4*)(av) = *(const float4*)&As[k][tm * 4];
      *(float4*)(bv) = *(const float4*)&Bs[k][tn * 4];
#pragma unroll
      for (int i = 0; i < 4; ++i)
#pragma unroll
        for (int j = 0; j < 4; ++j) acc[i][j] = fmaf(av[i], bv[j], acc[i][j]);
    }
    __syncthreads();
  }
#pragma unroll
  for (int i = 0; i < 4; ++i) {
    int row = m0 + tm * 4 + i;
    float o[4];
#pragma unroll
    for (int j = 0; j < 4; ++j) {
      float v = acc[i][j] + bias[n0 + tn * 4 + j];
      if (act == 1) v = fmaxf(v, 0.f);
      else if (act == 2) v = tanhf(v);
      o[j] = v;
    }
    *(float4*)(C + (size_t)row * N + n0 + tn * 4) = *(float4*)o;
  }
}

// ---------------------------------------------------------------------------
// Pack LSTM weights: wP[j][k][s] = w[(s*256+j)*256 + k] (s = i,f,g,o);
// bP[j][s] = bih[s*256+j] + bhh[s*256+j].  grid 256 (j), block 256 (k).
// ---------------------------------------------------------------------------
__global__ __launch_bounds__(256) void prep_pack(
    const float* __restrict__ wih, const float* __restrict__ whh,
    const float* __restrict__ bih, const float* __restrict__ bhh,
    float* __restrict__ wihP, float* __restrict__ whhP, float* __restrict__ bP)
{
  const int j = blockIdx.x, k = threadIdx.x;
  float4 a, c;
  a.x = wih[(0 * 256 + j) * 256 + k];
  a.y = wih[(1 * 256 + j) * 256 + k];
  a.z = wih[(2 * 256 + j) * 256 + k];
  a.w = wih[(3 * 256 + j) * 256 + k];
  *(float4*)&wihP[((size_t)j * 256 + k) * 4] = a;
  c.x = whh[(0 * 256 + j) * 256 + k];
  c.y = whh[(1 * 256 + j) * 256 + k];
  c.z = whh[(2 * 256 + j) * 256 + k];
  c.w = whh[(3 * 256 + j) * 256 + k];
  *(float4*)&whhP[((size_t)j * 256 + k) * 4] = c;
  if (k < 4) bP[j * 4 + k] = bih[k * 256 + j] + bhh[k * 256 + j];
}

// ---------------------------------------------------------------------------
// Per-slab 256x256 transpose: out[t][c][r] = in[t][r][c]. grid (T, 64), 256 thr.
// ---------------------------------------------------------------------------
__global__ __launch_bounds__(256) void transpose256(
    const float* __restrict__ in, float* __restrict__ out)
{
  const int t = blockIdx.x, c4 = blockIdx.y;
  const int r = threadIdx.x;
  float4 v = *(const float4*)(in + ((size_t)t * 256 + r) * 256 + c4 * 4);
  float* op = out + (size_t)t * 65536 + (size_t)(c4 * 4) * 256 + r;
  op[0]   = v.x;
  op[256] = v.y;
  op[512] = v.z;
  op[768] = v.w;
}

// ---------------------------------------------------------------------------
// LSTM cell, wave-per-j design.
// Grid 256 = bg(4) x jg(64), blockIdx = bg*64 + jg (same-jg weight sharers
// land on one XCD via %8). Block 256 thr = 4 waves; wave w owns j = jg*4+w
// (wave-uniform -> weights go down the SCALAR path via readfirstlane);
// the 64 lanes cover b = bg*64 + lane.
// h staged in LDS (64 KB, bank-conflict-free); x read coalesced from global.
// c in-place (thread-matched). All h/x tensors in [k][b] layout.
// ---------------------------------------------------------------------------
template <int HASX>
__global__ __launch_bounds__(256) void lstm_cell3(
    const float* __restrict__ xT,     // [256][256] (k,b)
    const float* __restrict__ wihP,   // [j][256][4]
    const float* __restrict__ whhP,   // [j][256][4]
    const float* __restrict__ bP,     // [j][4]
    const float* __restrict__ hT_in,  // [256][256] (k,b)
    float* __restrict__ cbuf,         // [256][256] (j,b), in-place
    float* __restrict__ hT_out,       // [256][256] (j,b)
    float* __restrict__ hT_copy)      // optional
{
  __shared__ float hs[256 * 64];
  const int jg = blockIdx.x & 63, bg = blockIdx.x >> 6;
  const int t = threadIdx.x;
  const int lane = t & 63;

  // stage h b-slice: [256][64] floats = 4096 float4
  {
    const float4* hg = (const float4*)hT_in;
    float4* hl = (float4*)hs;
#pragma unroll
    for (int n = 0; n < 16; ++n) {
      int v = n * 256 + t;
      int k = v >> 4, i = v & 15;
      hl[v] = hg[k * 64 + bg * 16 + i];
    }
  }
  __syncthreads();

  const int jw = __builtin_amdgcn_readfirstlane(jg * 4 + (t >> 6));
  const float4* wh = (const float4*)(whhP + (size_t)jw * 1024);
  const float4* wi = (const float4*)(wihP + (size_t)jw * 1024);
  const float* xcol = HASX ? (xT + bg * 64 + lane) : nullptr;
  float4 acc = *(const float4*)(bP + jw * 4);

#pragma unroll 8
  for (int k = 0; k < 256; ++k) {
    const float hv = hs[k * 64 + lane];
    const float4 wv = wh[k];
    acc.x = fmaf(hv, wv.x, acc.x);
    acc.y = fmaf(hv, wv.y, acc.y);
    acc.z = fmaf(hv, wv.z, acc.z);
    acc.w = fmaf(hv, wv.w, acc.w);
    if (HASX) {
      const float xv = xcol[k * 256];
      const float4 vv = wi[k];
      acc.x = fmaf(xv, vv.x, acc.x);
      acc.y = fmaf(xv, vv.y, acc.y);
      acc.z = fmaf(xv, vv.z, acc.z);
      acc.w = fmaf(xv, vv.w, acc.w);
    }
  }

  const int idx = jw * 256 + bg * 64 + lane;
  const float cold = cbuf[idx];
  const float ig = sigf(acc.x), fg = sigf(acc.y);
  const float gg = tanhf(acc.z), og = sigf(acc.w);
  const float cn = fg * cold + ig * gg;
  const float hn = og * tanhf(cn);
  cbuf[idx] = cn;
  hT_out[idx] = hn;
  if (hT_copy) hT_copy[idx] = hn;
}

// ---------------------------------------------------------------------------

extern "C" void kernel_launch(void* const* d_in, const int* in_sizes, int n_in,
                              void* d_out, int out_size, void* d_ws, size_t ws_size,
                              hipStream_t stream)
{
  const float* x_in  = (const float*)d_in[0];
  const float* w_en1 = (const float*)d_in[1];
  const float* b_en1 = (const float*)d_in[2];
  const float* w_en2 = (const float*)d_in[3];
  const float* b_en2 = (const float*)d_in[4];
  const float* cw[6][4];
  for (int i = 0; i < 6; ++i)
    for (int j = 0; j < 4; ++j) cw[i][j] = (const float*)d_in[5 + i * 4 + j];
  const float* w_de1 = (const float*)d_in[29];
  const float* b_de1 = (const float*)d_in[30];
  const float* w_de2 = (const float*)d_in[31];
  const float* b_de2 = (const float*)d_in[32];
  float* out = (float*)d_out;

  // ---- workspace layout (floats) ----
  float* ws   = (float*)d_ws;
  float* wihP = ws;                        // 6 * 262144
  float* whhP = wihP + 6 * 262144;         // 6 * 262144
  float* bP   = whhP + 6 * 262144;         // 6 * 1024
  float* hb   = bP + 6 * 1024;             // 12 * 65536 (6 layers x ping-pong)
  float* cb   = hb + 12 * 65536;           // 6 * 65536
  float* H3T  = cb + 6 * 65536;            // 10 * 65536
  float* R1   = H3T + 10 * 65536;          // 5,242,880: z1 -> z2T | (H3std, y1)
  float* R2   = R1 + 5242880;              // 1,310,720: z2

  // ---- weight packing + zero states (every call) ----
  for (int i = 0; i < 6; ++i)
    prep_pack<<<256, 256, 0, stream>>>(cw[i][0], cw[i][1], cw[i][2], cw[i][3],
                                       wihP + i * 262144, whhP + i * 262144,
                                       bP + i * 1024);
  hipMemsetAsync(hb, 0, (size_t)18 * 65536 * sizeof(float), stream);

  // ---- batched encoder feedforward ----
  float* z1  = R1;
  float* z2  = R2;
  float* z2T = R1;  // z1 dead after fc_en2
  gemm64<<<dim3(5120 / 64, 1024 / 64), 256, 0, stream>>>(
      x_in, w_en1, b_en1, z1, 5120, 1024, 4096, 1);
  gemm64<<<dim3(5120 / 64, 256 / 64), 256, 0, stream>>>(
      z1, w_en2, b_en2, z2, 5120, 256, 1024, 1);
  transpose256<<<dim3(20, 64), 256, 0, stream>>>(z2, z2T);  // [t][b][k]->[t][k][b]

  // ---- recurrence: 90 cell launches ----
  int pp[6] = {0, 0, 0, 0, 0, 0};
  auto HBuf = [&](int l, int p) { return hb + (size_t)(l * 2 + p) * 65536; };
  auto CBuf = [&](int l) { return cb + (size_t)l * 65536; };

  auto cellX = [&](const float* xT, int l, float* copy) {
    lstm_cell3<1><<<256, 256, 0, stream>>>(
        xT, wihP + l * 262144, whhP + l * 262144, bP + l * 1024,
        HBuf(l, pp[l]), CBuf(l), HBuf(l, pp[l] ^ 1), copy);
    pp[l] ^= 1;
  };

  for (int t = 0; t < 20; ++t) {
    cellX(z2T + (size_t)t * 65536, 0, nullptr);
    cellX(HBuf(0, pp[0]), 1, nullptr);
    cellX(HBuf(1, pp[1]), 2, nullptr);
  }
  for (int s = 0; s < 10; ++s) {
    const float* h1in = (s == 0) ? HBuf(2, pp[2]) : HBuf(3, pp[3]);
    lstm_cell3<0><<<256, 256, 0, stream>>>(
        nullptr, wihP + 3 * 262144, whhP + 3 * 262144, bP + 3 * 1024,
        h1in, CBuf(3), HBuf(3, pp[3] ^ 1), nullptr);
    pp[3] ^= 1;
    cellX(HBuf(3, pp[3]), 4, nullptr);
    cellX(HBuf(4, pp[4]), 5, H3T + (size_t)s * 65536);
  }

  // ---- batched decoder output FCs ----
  float* H3std = R1;             // [s*256+b][j]
  float* y1    = R1 + 1310720;   // 2560 x 1024
  transpose256<<<dim3(10, 64), 256, 0, stream>>>(H3T, H3std);  // [s][j][b]->[s][b][j]
  gemm64<<<dim3(2560 / 64, 1024 / 64), 256, 0, stream>>>(
      H3std, w_de1, b_de1, y1, 2560, 1024, 256, 1);
  gemm128x64<<<dim3(2560 / 128, 4096 / 64), 256, 0, stream>>>(
      y1, w_de2, b_de2, out, 2560, 4096, 1024, 2);

  (void)in_sizes; (void)n_in; (void)out_size; (void)ws_size;
}

// Round 9
// 1024.445 us; speedup vs baseline: 5.6849x; 2.0442x over previous
//
#include <hip/hip_runtime.h>
#include <math.h>

static __device__ __forceinline__ float sigf(float v) { return 1.0f / (1.0f + expf(-v)); }

using s8v  = __attribute__((ext_vector_type(8))) short;   // 8 bf16 (4 VGPR)
using f4v  = __attribute__((ext_vector_type(4))) float;   // MFMA acc

static __device__ __forceinline__ void splitf(float f, unsigned short& h, unsigned short& l) {
  unsigned u = __float_as_uint(f);
  unsigned short hb = (unsigned short)((u + 0x7FFFu + ((u >> 16) & 1u)) >> 16);
  float hf = __uint_as_float(((unsigned)hb) << 16);
  float lf = f - hf;
  unsigned ul = __float_as_uint(lf);
  unsigned short lb = (unsigned short)((ul + 0x7FFFu + ((ul >> 16) & 1u)) >> 16);
  h = hb; l = lb;
}

// ---------------------------------------------------------------------------
// Split-bf16 MFMA GEMM: C[M,N] = act(A[M,K] @ W[N,K]^T + bias[N])
// A,W fp32; on-the-fly 2-way bf16 split; 3 MFMA passes (hh, hl, lh).
// Block 256 thr = 4 waves; tile 128(M) x 64(N); wave = 32m x 64n; BK=32.
// LDS rows padded to 40 bf16 (80 B): b128 frag reads bank-conflict-free.
// act: 1=relu, 2=tanh. Requires M%128==0, N%64==0, K%32==0.
// ---------------------------------------------------------------------------
__global__ __launch_bounds__(256) void gemm_mfma(
    const float* __restrict__ A, const float* __restrict__ W,
    const float* __restrict__ bias, float* __restrict__ C,
    int M, int N, int K, int act)
{
  __shared__ unsigned short AsH[128 * 40];
  __shared__ unsigned short AsL[128 * 40];
  __shared__ unsigned short WsH[64 * 40];
  __shared__ unsigned short WsL[64 * 40];

  const int t = threadIdx.x;
  const int w = t >> 6, lane = t & 63;
  const int lrow = lane & 15, lk = (lane >> 4) * 8;
  const int m0 = blockIdx.x * 128, n0 = blockIdx.y * 64;

  f4v acc[2][4];
#pragma unroll
  for (int i = 0; i < 2; ++i)
#pragma unroll
    for (int j = 0; j < 4; ++j) acc[i][j] = (f4v){0.f, 0.f, 0.f, 0.f};

  for (int k0 = 0; k0 < K; k0 += 32) {
    // ---- stage: global fp32 -> split bf16 hi/lo -> LDS ----
#pragma unroll
    for (int i = 0; i < 4; ++i) {
      int v = i * 256 + t;                 // 0..1023
      int row = v >> 3, kq = (v & 7) << 2; // 128 rows x 8 float4
      float4 a = *(const float4*)(A + (size_t)(m0 + row) * K + k0 + kq);
      ushort4 h4, l4;
      splitf(a.x, h4.x, l4.x); splitf(a.y, h4.y, l4.y);
      splitf(a.z, h4.z, l4.z); splitf(a.w, h4.w, l4.w);
      *(ushort4*)&AsH[row * 40 + kq] = h4;
      *(ushort4*)&AsL[row * 40 + kq] = l4;
    }
#pragma unroll
    for (int i = 0; i < 2; ++i) {
      int v = i * 256 + t;                 // 0..511
      int row = v >> 3, kq = (v & 7) << 2; // 64 rows x 8 float4
      float4 b = *(const float4*)(W + (size_t)(n0 + row) * K + k0 + kq);
      ushort4 h4, l4;
      splitf(b.x, h4.x, l4.x); splitf(b.y, h4.y, l4.y);
      splitf(b.z, h4.z, l4.z); splitf(b.w, h4.w, l4.w);
      *(ushort4*)&WsH[row * 40 + kq] = h4;
      *(ushort4*)&WsL[row * 40 + kq] = l4;
    }
    __syncthreads();

    // ---- fragments ----
    s8v aH[2], aL[2], bH[4], bL[4];
#pragma unroll
    for (int mt = 0; mt < 2; ++mt) {
      int r = (w * 32 + mt * 16 + lrow) * 40 + lk;
      aH[mt] = *(const s8v*)&AsH[r];
      aL[mt] = *(const s8v*)&AsL[r];
    }
#pragma unroll
    for (int nt = 0; nt < 4; ++nt) {
      int r = (nt * 16 + lrow) * 40 + lk;
      bH[nt] = *(const s8v*)&WsH[r];
      bL[nt] = *(const s8v*)&WsL[r];
    }

    // ---- 3-pass MFMA ----
#pragma unroll
    for (int mt = 0; mt < 2; ++mt)
#pragma unroll
      for (int nt = 0; nt < 4; ++nt) {
        acc[mt][nt] = __builtin_amdgcn_mfma_f32_16x16x32_bf16(aH[mt], bH[nt], acc[mt][nt], 0, 0, 0);
        acc[mt][nt] = __builtin_amdgcn_mfma_f32_16x16x32_bf16(aH[mt], bL[nt], acc[mt][nt], 0, 0, 0);
        acc[mt][nt] = __builtin_amdgcn_mfma_f32_16x16x32_bf16(aL[mt], bH[nt], acc[mt][nt], 0, 0, 0);
      }
    __syncthreads();
  }

  // ---- epilogue: C/D map col=lane&15, row=(lane>>4)*4+reg ----
#pragma unroll
  for (int mt = 0; mt < 2; ++mt)
#pragma unroll
    for (int nt = 0; nt < 4; ++nt) {
      int gcol = n0 + nt * 16 + lrow;
      float bv = bias[gcol];
#pragma unroll
      for (int r = 0; r < 4; ++r) {
        int grow = m0 + w * 32 + mt * 16 + (lane >> 4) * 4 + r;
        float v = acc[mt][nt][r] + bv;
        if (act == 1) v = fmaxf(v, 0.f);
        else if (act == 2) v = tanhf(v);
        C[(size_t)grow * N + gcol] = v;
      }
    }
}

// ---------------------------------------------------------------------------
// 64x64 tile fp32 GEMM (for the small FCs). C = act(A @ W^T + bias).
// ---------------------------------------------------------------------------
__global__ __launch_bounds__(256) void gemm64(
    const float* __restrict__ A, const float* __restrict__ Bw,
    const float* __restrict__ bias, float* __restrict__ C,
    int M, int N, int K, int act)
{
  __shared__ float As[16][68];
  __shared__ float Bs[16][68];
  const int tid = threadIdx.x;
  const int tm = tid & 15, tn = tid >> 4;
  const int m0 = blockIdx.x * 64, n0 = blockIdx.y * 64;
  float acc[4][4];
#pragma unroll
  for (int i = 0; i < 4; ++i)
#pragma unroll
    for (int j = 0; j < 4; ++j) acc[i][j] = 0.f;

  for (int k0 = 0; k0 < K; k0 += 16) {
    {
      int row = tid >> 2, kc = (tid & 3) << 2;
      float4 a = *(const float4*)(A + (size_t)(m0 + row) * K + k0 + kc);
      As[kc + 0][row] = a.x; As[kc + 1][row] = a.y;
      As[kc + 2][row] = a.z; As[kc + 3][row] = a.w;
      float4 b = *(const float4*)(Bw + (size_t)(n0 + row) * K + k0 + kc);
      Bs[kc + 0][row] = b.x; Bs[kc + 1][row] = b.y;
      Bs[kc + 2][row] = b.z; Bs[kc + 3][row] = b.w;
    }
    __syncthreads();
#pragma unroll
    for (int k = 0; k < 16; ++k) {
      float av[4], bv[4];
      *(float4*)(av) = *(const float4*)&As[k][tm * 4];
      *(float4*)(bv) = *(const float4*)&Bs[k][tn * 4];
#pragma unroll
      for (int i = 0; i < 4; ++i)
#pragma unroll
        for (int j = 0; j < 4; ++j) acc[i][j] = fmaf(av[i], bv[j], acc[i][j]);
    }
    __syncthreads();
  }
#pragma unroll
  for (int i = 0; i < 4; ++i) {
    int row = m0 + tm * 4 + i;
    float o[4];
#pragma unroll
    for (int j = 0; j < 4; ++j) {
      float v = acc[i][j] + bias[n0 + tn * 4 + j];
      if (act == 1) v = fmaxf(v, 0.f);
      else if (act == 2) v = tanhf(v);
      o[j] = v;
    }
    *(float4*)(C + (size_t)row * N + n0 + tn * 4) = *(float4*)o;
  }
}

// ---------------------------------------------------------------------------
// Pack LSTM weights: wP[j][k][s] = w[(s*256+j)*256 + k] (s = i,f,g,o);
// bP[j][s] = bih[s*256+j] + bhh[s*256+j].  grid 256 (j), block 256 (k).
// ---------------------------------------------------------------------------
__global__ __launch_bounds__(256) void prep_pack(
    const float* __restrict__ wih, const float* __restrict__ whh,
    const float* __restrict__ bih, const float* __restrict__ bhh,
    float* __restrict__ wihP, float* __restrict__ whhP, float* __restrict__ bP)
{
  const int j = blockIdx.x, k = threadIdx.x;
  float4 a, c;
  a.x = wih[(0 * 256 + j) * 256 + k];
  a.y = wih[(1 * 256 + j) * 256 + k];
  a.z = wih[(2 * 256 + j) * 256 + k];
  a.w = wih[(3 * 256 + j) * 256 + k];
  *(float4*)&wihP[((size_t)j * 256 + k) * 4] = a;
  c.x = whh[(0 * 256 + j) * 256 + k];
  c.y = whh[(1 * 256 + j) * 256 + k];
  c.z = whh[(2 * 256 + j) * 256 + k];
  c.w = whh[(3 * 256 + j) * 256 + k];
  *(float4*)&whhP[((size_t)j * 256 + k) * 4] = c;
  if (k < 4) bP[j * 4 + k] = bih[k * 256 + j] + bhh[k * 256 + j];
}

// ---------------------------------------------------------------------------
// Per-slab 256x256 transpose: out[t][c][r] = in[t][r][c]. grid (T, 64), 256 thr.
// ---------------------------------------------------------------------------
__global__ __launch_bounds__(256) void transpose256(
    const float* __restrict__ in, float* __restrict__ out)
{
  const int t = blockIdx.x, c4 = blockIdx.y;
  const int r = threadIdx.x;
  float4 v = *(const float4*)(in + ((size_t)t * 256 + r) * 256 + c4 * 4);
  float* op = out + (size_t)t * 65536 + (size_t)(c4 * 4) * 256 + r;
  op[0]   = v.x;
  op[256] = v.y;
  op[512] = v.z;
  op[768] = v.w;
}

// ---------------------------------------------------------------------------
// Multi-slot LSTM cell kernel: up to 3 INDEPENDENT cells (pipelined layers)
// per launch. Slot = blockIdx.x>>8. Within a slot: 256 blocks = bg(4)-major
// x jg(64); block 256 thr = 4 waves; wave owns j = jg*4+wave (scalar-path
// weights), lanes cover b = bg*64+lane. No LDS: h/x read coalesced from
// global (L2), weights via s_load. c in-place. All h/x in [k][b] layout.
// ---------------------------------------------------------------------------
struct CellSlot {
  const float* x;     // [256][256] (k,b) or null
  const float* wih;   // [j][256][4]
  const float* whh;   // [j][256][4]
  const float* bias;  // [j][4]
  const float* hin;   // [256][256] (k,b)
  float* c;           // [256][256] (j,b) in-place
  float* hout;        // [256][256] (j,b)
  float* hcopy;       // optional
  int hasx;
};
struct CellArgs { CellSlot s[3]; };

__global__ __launch_bounds__(256) void cell_multi(CellArgs args)
{
  const CellSlot S = args.s[blockIdx.x >> 8];
  const int inner = blockIdx.x & 255;
  const int jg = inner & 63, bg = inner >> 6;
  const int t = threadIdx.x;
  const int lane = t & 63;
  const int b = bg * 64 + lane;

  const int jw = __builtin_amdgcn_readfirstlane(jg * 4 + (t >> 6));
  const float4* wh = (const float4*)(S.whh + (size_t)jw * 1024);
  const float4* wi = (const float4*)(S.wih + (size_t)jw * 1024);
  const float* hcol = S.hin + b;
  float4 acc = *(const float4*)(S.bias + jw * 4);

  if (S.hasx) {
    const float* xcol = S.x + b;
#pragma unroll 8
    for (int k = 0; k < 256; ++k) {
      const float hv = hcol[k * 256];
      const float4 wv = wh[k];
      acc.x = fmaf(hv, wv.x, acc.x);
      acc.y = fmaf(hv, wv.y, acc.y);
      acc.z = fmaf(hv, wv.z, acc.z);
      acc.w = fmaf(hv, wv.w, acc.w);
      const float xv = xcol[k * 256];
      const float4 vv = wi[k];
      acc.x = fmaf(xv, vv.x, acc.x);
      acc.y = fmaf(xv, vv.y, acc.y);
      acc.z = fmaf(xv, vv.z, acc.z);
      acc.w = fmaf(xv, vv.w, acc.w);
    }
  } else {
#pragma unroll 8
    for (int k = 0; k < 256; ++k) {
      const float hv = hcol[k * 256];
      const float4 wv = wh[k];
      acc.x = fmaf(hv, wv.x, acc.x);
      acc.y = fmaf(hv, wv.y, acc.y);
      acc.z = fmaf(hv, wv.z, acc.z);
      acc.w = fmaf(hv, wv.w, acc.w);
    }
  }

  const int idx = jw * 256 + b;
  const float cold = S.c[idx];
  const float ig = sigf(acc.x), fg = sigf(acc.y);
  const float gg = tanhf(acc.z), og = sigf(acc.w);
  const float cn = fg * cold + ig * gg;
  const float hn = og * tanhf(cn);
  S.c[idx] = cn;
  S.hout[idx] = hn;
  if (S.hcopy) S.hcopy[idx] = hn;
}

// ---------------------------------------------------------------------------

extern "C" void kernel_launch(void* const* d_in, const int* in_sizes, int n_in,
                              void* d_out, int out_size, void* d_ws, size_t ws_size,
                              hipStream_t stream)
{
  const float* x_in  = (const float*)d_in[0];
  const float* w_en1 = (const float*)d_in[1];
  const float* b_en1 = (const float*)d_in[2];
  const float* w_en2 = (const float*)d_in[3];
  const float* b_en2 = (const float*)d_in[4];
  const float* cw[6][4];
  for (int i = 0; i < 6; ++i)
    for (int j = 0; j < 4; ++j) cw[i][j] = (const float*)d_in[5 + i * 4 + j];
  const float* w_de1 = (const float*)d_in[29];
  const float* b_de1 = (const float*)d_in[30];
  const float* w_de2 = (const float*)d_in[31];
  const float* b_de2 = (const float*)d_in[32];
  float* out = (float*)d_out;

  // ---- workspace layout (floats) ----
  float* ws   = (float*)d_ws;
  float* wihP = ws;                        // 6 * 262144
  float* whhP = wihP + 6 * 262144;         // 6 * 262144
  float* bP   = whhP + 6 * 262144;         // 6 * 1024
  float* hb   = bP + 6 * 1024;             // 12 * 65536 (6 layers x ping-pong)
  float* cb   = hb + 12 * 65536;           // 6 * 65536
  float* H3T  = cb + 6 * 65536;            // 10 * 65536
  float* R1   = H3T + 10 * 65536;          // 5,242,880: z1 -> z2T | (H3std, y1)
  float* R2   = R1 + 5242880;              // 1,310,720: z2

  // ---- weight packing + zero states (every call) ----
  for (int i = 0; i < 6; ++i)
    prep_pack<<<256, 256, 0, stream>>>(cw[i][0], cw[i][1], cw[i][2], cw[i][3],
                                       wihP + i * 262144, whhP + i * 262144,
                                       bP + i * 1024);
  hipMemsetAsync(hb, 0, (size_t)18 * 65536 * sizeof(float), stream);

  // ---- batched encoder feedforward ----
  float* z1  = R1;
  float* z2  = R2;
  float* z2T = R1;  // z1 dead after fc_en2
  gemm_mfma<<<dim3(5120 / 128, 1024 / 64), 256, 0, stream>>>(
      x_in, w_en1, b_en1, z1, 5120, 1024, 4096, 1);
  gemm64<<<dim3(5120 / 64, 256 / 64), 256, 0, stream>>>(
      z1, w_en2, b_en2, z2, 5120, 256, 1024, 1);
  transpose256<<<dim3(20, 64), 256, 0, stream>>>(z2, z2T);  // [t][b][k]->[t][k][b]

  // ---- recurrence: layer-pipelined cell launches ----
  int pp[6] = {0, 0, 0, 0, 0, 0};
  auto HBuf = [&](int l, int p) { return hb + (size_t)(l * 2 + p) * 65536; };
  auto CBuf = [&](int l) { return cb + (size_t)l * 65536; };
  auto WI = [&](int l) { return wihP + (size_t)l * 262144; };
  auto WH = [&](int l) { return whhP + (size_t)l * 262144; };
  auto BB = [&](int l) { return bP + (size_t)l * 1024; };

  // encoder: stages 0..21; active: en1 @t=s (s<20), en2 @t=s-1, en3 @t=s-2
  for (int s = 0; s <= 21; ++s) {
    CellArgs a; int n = 0; int tog[3]; int nt = 0;
    if (s < 20) {
      a.s[n++] = {z2T + (size_t)s * 65536, WI(0), WH(0), BB(0),
                  HBuf(0, pp[0]), CBuf(0), HBuf(0, pp[0] ^ 1), nullptr, 1};
      tog[nt++] = 0;
    }
    if (s >= 1 && s <= 20) {
      a.s[n++] = {HBuf(0, pp[0]), WI(1), WH(1), BB(1),
                  HBuf(1, pp[1]), CBuf(1), HBuf(1, pp[1] ^ 1), nullptr, 1};
      tog[nt++] = 1;
    }
    if (s >= 2) {
      a.s[n++] = {HBuf(1, pp[1]), WI(2), WH(2), BB(2),
                  HBuf(2, pp[2]), CBuf(2), HBuf(2, pp[2] ^ 1), nullptr, 1};
      tog[nt++] = 2;
    }
    cell_multi<<<n * 256, 256, 0, stream>>>(a);
    for (int i = 0; i < nt; ++i) pp[tog[i]] ^= 1;
  }

  // decoder: stages 0..11; de1 @t=s (s<10, x=0), de2 @t=s-1, de3 @t=s-2
  for (int s = 0; s <= 11; ++s) {
    CellArgs a; int n = 0; int tog[3]; int nt = 0;
    if (s < 10) {
      const float* h1in = (s == 0) ? HBuf(2, pp[2]) : HBuf(3, pp[3]);
      a.s[n++] = {nullptr, WI(3), WH(3), BB(3),
                  h1in, CBuf(3), HBuf(3, pp[3] ^ 1), nullptr, 0};
      tog[nt++] = 3;
    }
    if (s >= 1 && s <= 10) {
      a.s[n++] = {HBuf(3, pp[3]), WI(4), WH(4), BB(4),
                  HBuf(4, pp[4]), CBuf(4), HBuf(4, pp[4] ^ 1), nullptr, 1};
      tog[nt++] = 4;
    }
    if (s >= 2) {
      a.s[n++] = {HBuf(4, pp[4]), WI(5), WH(5), BB(5),
                  HBuf(5, pp[5]), CBuf(5), HBuf(5, pp[5] ^ 1),
                  H3T + (size_t)(s - 2) * 65536, 1};
      tog[nt++] = 5;
    }
    cell_multi<<<n * 256, 256, 0, stream>>>(a);
    for (int i = 0; i < nt; ++i) pp[tog[i]] ^= 1;
  }

  // ---- batched decoder output FCs ----
  float* H3std = R1;             // [s*256+b][j]
  float* y1    = R1 + 1310720;   // 2560 x 1024
  transpose256<<<dim3(10, 64), 256, 0, stream>>>(H3T, H3std);  // [s][j][b]->[s][b][j]
  gemm64<<<dim3(2560 / 64, 1024 / 64), 256, 0, stream>>>(
      H3std, w_de1, b_de1, y1, 2560, 1024, 256, 1);
  gemm_mfma<<<dim3(2560 / 128, 4096 / 64), 256, 0, stream>>>(
      y1, w_de2, b_de2, out, 2560, 4096, 1024, 2);

  (void)in_sizes; (void)n_in; (void)out_size; (void)ws_size;
}

// Round 10
// 945.525 us; speedup vs baseline: 6.1594x; 1.0835x over previous
//
#include <hip/hip_runtime.h>
#include <math.h>

static __device__ __forceinline__ float sigf(float v) { return 1.0f / (1.0f + expf(-v)); }

using s8v = __attribute__((ext_vector_type(8))) short;   // 8 bf16 (4 VGPR)
using f4v = __attribute__((ext_vector_type(4))) float;   // MFMA acc

static __device__ __forceinline__ void splitf(float f, unsigned short& h, unsigned short& l) {
  unsigned u = __float_as_uint(f);
  unsigned short hb = (unsigned short)((u + 0x7FFFu + ((u >> 16) & 1u)) >> 16);
  float hf = __uint_as_float(((unsigned)hb) << 16);
  float lf = f - hf;
  unsigned ul = __float_as_uint(lf);
  unsigned short lb = (unsigned short)((ul + 0x7FFFu + ((ul >> 16) & 1u)) >> 16);
  h = hb; l = lb;
}

// ---------------------------------------------------------------------------
// One-time weight split: W f32 -> WH/WL bf16 (ushort). n4 = elems/4.
// ---------------------------------------------------------------------------
__global__ __launch_bounds__(256) void wsplit(
    const float* __restrict__ W, unsigned short* __restrict__ WH,
    unsigned short* __restrict__ WL, int n4)
{
  int i = blockIdx.x * 256 + threadIdx.x;
  if (i < n4) {
    float4 v = ((const float4*)W)[i];
    ushort4 h, l;
    splitf(v.x, h.x, l.x); splitf(v.y, h.y, l.y);
    splitf(v.z, h.z, l.z); splitf(v.w, h.w, l.w);
    ((ushort4*)WH)[i] = h;
    ((ushort4*)WL)[i] = l;
  }
}

// ---------------------------------------------------------------------------
// MFMA GEMM, A fp32 split on the fly, W pre-split.
// C/out = act(A[M,K] @ W[N,K]^T + bias). Tile 128x64, BK=32, 4 waves.
// OSPLIT=1: write bf16 hi/lo pair (act applied first). act: 1=relu, 2=tanh.
// ---------------------------------------------------------------------------
template <int OSPLIT>
__global__ __launch_bounds__(256) void gemm_sf(
    const float* __restrict__ A,
    const unsigned short* __restrict__ WH, const unsigned short* __restrict__ WL,
    const float* __restrict__ bias, float* __restrict__ C,
    unsigned short* __restrict__ OH, unsigned short* __restrict__ OL,
    int M, int N, int K, int act)
{
  __shared__ unsigned short AsH[128 * 40];
  __shared__ unsigned short AsL[128 * 40];
  __shared__ unsigned short WsH[64 * 40];
  __shared__ unsigned short WsL[64 * 40];

  const int t = threadIdx.x;
  const int w = t >> 6, lane = t & 63;
  const int lrow = lane & 15, lk = (lane >> 4) * 8;
  const int m0 = blockIdx.x * 128, n0 = blockIdx.y * 64;

  f4v acc[2][4];
#pragma unroll
  for (int i = 0; i < 2; ++i)
#pragma unroll
    for (int j = 0; j < 4; ++j) acc[i][j] = (f4v){0.f, 0.f, 0.f, 0.f};

  for (int k0 = 0; k0 < K; k0 += 32) {
#pragma unroll
    for (int i = 0; i < 4; ++i) {
      int v = i * 256 + t;
      int row = v >> 3, kq = (v & 7) << 2;
      float4 a = *(const float4*)(A + (size_t)(m0 + row) * K + k0 + kq);
      ushort4 h4, l4;
      splitf(a.x, h4.x, l4.x); splitf(a.y, h4.y, l4.y);
      splitf(a.z, h4.z, l4.z); splitf(a.w, h4.w, l4.w);
      *(ushort4*)&AsH[row * 40 + kq] = h4;
      *(ushort4*)&AsL[row * 40 + kq] = l4;
    }
    {
      int row = t >> 2, q = (t & 3) * 8;
      *(s8v*)&WsH[row * 40 + q] = *(const s8v*)(WH + (size_t)(n0 + row) * K + k0 + q);
      *(s8v*)&WsL[row * 40 + q] = *(const s8v*)(WL + (size_t)(n0 + row) * K + k0 + q);
    }
    __syncthreads();

    s8v aH[2], aL[2], bH[4], bL[4];
#pragma unroll
    for (int mt = 0; mt < 2; ++mt) {
      int r = (w * 32 + mt * 16 + lrow) * 40 + lk;
      aH[mt] = *(const s8v*)&AsH[r];
      aL[mt] = *(const s8v*)&AsL[r];
    }
#pragma unroll
    for (int nt = 0; nt < 4; ++nt) {
      int r = (nt * 16 + lrow) * 40 + lk;
      bH[nt] = *(const s8v*)&WsH[r];
      bL[nt] = *(const s8v*)&WsL[r];
    }
#pragma unroll
    for (int mt = 0; mt < 2; ++mt)
#pragma unroll
      for (int nt = 0; nt < 4; ++nt) {
        acc[mt][nt] = __builtin_amdgcn_mfma_f32_16x16x32_bf16(aH[mt], bH[nt], acc[mt][nt], 0, 0, 0);
        acc[mt][nt] = __builtin_amdgcn_mfma_f32_16x16x32_bf16(aH[mt], bL[nt], acc[mt][nt], 0, 0, 0);
        acc[mt][nt] = __builtin_amdgcn_mfma_f32_16x16x32_bf16(aL[mt], bH[nt], acc[mt][nt], 0, 0, 0);
      }
    __syncthreads();
  }

#pragma unroll
  for (int mt = 0; mt < 2; ++mt)
#pragma unroll
    for (int nt = 0; nt < 4; ++nt) {
      int gcol = n0 + nt * 16 + lrow;
      float bv = bias[gcol];
#pragma unroll
      for (int r = 0; r < 4; ++r) {
        int grow = m0 + w * 32 + mt * 16 + (lane >> 4) * 4 + r;
        float v = acc[mt][nt][r] + bv;
        if (act == 1) v = fmaxf(v, 0.f);
        else if (act == 2) v = tanhf(v);
        if (OSPLIT) {
          unsigned short h, l;
          splitf(v, h, l);
          OH[(size_t)grow * N + gcol] = h;
          OL[(size_t)grow * N + gcol] = l;
        } else {
          C[(size_t)grow * N + gcol] = v;
        }
      }
    }
}

// ---------------------------------------------------------------------------
// MFMA GEMM, A AND W pre-split bf16. Same contract/tiling as gemm_sf.
// ---------------------------------------------------------------------------
template <int OSPLIT>
__global__ __launch_bounds__(256) void gemm_bb(
    const unsigned short* __restrict__ AH, const unsigned short* __restrict__ AL,
    const unsigned short* __restrict__ WH, const unsigned short* __restrict__ WL,
    const float* __restrict__ bias, float* __restrict__ C,
    unsigned short* __restrict__ OH, unsigned short* __restrict__ OL,
    int M, int N, int K, int act)
{
  __shared__ unsigned short AsH[128 * 40];
  __shared__ unsigned short AsL[128 * 40];
  __shared__ unsigned short WsH[64 * 40];
  __shared__ unsigned short WsL[64 * 40];

  const int t = threadIdx.x;
  const int w = t >> 6, lane = t & 63;
  const int lrow = lane & 15, lk = (lane >> 4) * 8;
  const int m0 = blockIdx.x * 128, n0 = blockIdx.y * 64;

  f4v acc[2][4];
#pragma unroll
  for (int i = 0; i < 2; ++i)
#pragma unroll
    for (int j = 0; j < 4; ++j) acc[i][j] = (f4v){0.f, 0.f, 0.f, 0.f};

  for (int k0 = 0; k0 < K; k0 += 32) {
#pragma unroll
    for (int i = 0; i < 2; ++i) {
      int v = i * 256 + t;
      int row = v >> 2, q = (v & 3) * 8;  // 128 rows x 4 ushort8
      *(s8v*)&AsH[row * 40 + q] = *(const s8v*)(AH + (size_t)(m0 + row) * K + k0 + q);
      *(s8v*)&AsL[row * 40 + q] = *(const s8v*)(AL + (size_t)(m0 + row) * K + k0 + q);
    }
    {
      int row = t >> 2, q = (t & 3) * 8;  // 64 rows x 4 ushort8
      *(s8v*)&WsH[row * 40 + q] = *(const s8v*)(WH + (size_t)(n0 + row) * K + k0 + q);
      *(s8v*)&WsL[row * 40 + q] = *(const s8v*)(WL + (size_t)(n0 + row) * K + k0 + q);
    }
    __syncthreads();

    s8v aH[2], aL[2], bH[4], bL[4];
#pragma unroll
    for (int mt = 0; mt < 2; ++mt) {
      int r = (w * 32 + mt * 16 + lrow) * 40 + lk;
      aH[mt] = *(const s8v*)&AsH[r];
      aL[mt] = *(const s8v*)&AsL[r];
    }
#pragma unroll
    for (int nt = 0; nt < 4; ++nt) {
      int r = (nt * 16 + lrow) * 40 + lk;
      bH[nt] = *(const s8v*)&WsH[r];
      bL[nt] = *(const s8v*)&WsL[r];
    }
#pragma unroll
    for (int mt = 0; mt < 2; ++mt)
#pragma unroll
      for (int nt = 0; nt < 4; ++nt) {
        acc[mt][nt] = __builtin_amdgcn_mfma_f32_16x16x32_bf16(aH[mt], bH[nt], acc[mt][nt], 0, 0, 0);
        acc[mt][nt] = __builtin_amdgcn_mfma_f32_16x16x32_bf16(aH[mt], bL[nt], acc[mt][nt], 0, 0, 0);
        acc[mt][nt] = __builtin_amdgcn_mfma_f32_16x16x32_bf16(aL[mt], bH[nt], acc[mt][nt], 0, 0, 0);
      }
    __syncthreads();
  }

#pragma unroll
  for (int mt = 0; mt < 2; ++mt)
#pragma unroll
    for (int nt = 0; nt < 4; ++nt) {
      int gcol = n0 + nt * 16 + lrow;
      float bv = bias[gcol];
#pragma unroll
      for (int r = 0; r < 4; ++r) {
        int grow = m0 + w * 32 + mt * 16 + (lane >> 4) * 4 + r;
        float v = acc[mt][nt][r] + bv;
        if (act == 1) v = fmaxf(v, 0.f);
        else if (act == 2) v = tanhf(v);
        if (OSPLIT) {
          unsigned short h, l;
          splitf(v, h, l);
          OH[(size_t)grow * N + gcol] = h;
          OL[(size_t)grow * N + gcol] = l;
        } else {
          C[(size_t)grow * N + gcol] = v;
        }
      }
    }
}

// ---------------------------------------------------------------------------
// Pack LSTM weights: wP[j][k][s] = w[(s*256+j)*256 + k] (s = i,f,g,o);
// bP[j][s] = bih[s*256+j] + bhh[s*256+j].  grid 256 (j), block 256 (k).
// ---------------------------------------------------------------------------
__global__ __launch_bounds__(256) void prep_pack(
    const float* __restrict__ wih, const float* __restrict__ whh,
    const float* __restrict__ bih, const float* __restrict__ bhh,
    float* __restrict__ wihP, float* __restrict__ whhP, float* __restrict__ bP)
{
  const int j = blockIdx.x, k = threadIdx.x;
  float4 a, c;
  a.x = wih[(0 * 256 + j) * 256 + k];
  a.y = wih[(1 * 256 + j) * 256 + k];
  a.z = wih[(2 * 256 + j) * 256 + k];
  a.w = wih[(3 * 256 + j) * 256 + k];
  *(float4*)&wihP[((size_t)j * 256 + k) * 4] = a;
  c.x = whh[(0 * 256 + j) * 256 + k];
  c.y = whh[(1 * 256 + j) * 256 + k];
  c.z = whh[(2 * 256 + j) * 256 + k];
  c.w = whh[(3 * 256 + j) * 256 + k];
  *(float4*)&whhP[((size_t)j * 256 + k) * 4] = c;
  if (k < 4) bP[j * 4 + k] = bih[k * 256 + j] + bhh[k * 256 + j];
}

// ---------------------------------------------------------------------------
// Per-slab 256x256 transpose (f32): out[t][c][r] = in[t][r][c].
// ---------------------------------------------------------------------------
__global__ __launch_bounds__(256) void transpose256(
    const float* __restrict__ in, float* __restrict__ out)
{
  const int t = blockIdx.x, c4 = blockIdx.y;
  const int r = threadIdx.x;
  float4 v = *(const float4*)(in + ((size_t)t * 256 + r) * 256 + c4 * 4);
  float* op = out + (size_t)t * 65536 + (size_t)(c4 * 4) * 256 + r;
  op[0]   = v.x;
  op[256] = v.y;
  op[512] = v.z;
  op[768] = v.w;
}

// ---------------------------------------------------------------------------
// Transpose + bf16-split: outH/L[t][c][r] = split(in[t][r][c]).
// ---------------------------------------------------------------------------
__global__ __launch_bounds__(256) void transpose256s(
    const float* __restrict__ in, unsigned short* __restrict__ outH,
    unsigned short* __restrict__ outL)
{
  const int t = blockIdx.x, c4 = blockIdx.y;
  const int r = threadIdx.x;
  float4 v = *(const float4*)(in + ((size_t)t * 256 + r) * 256 + c4 * 4);
  ushort4 h, l;
  splitf(v.x, h.x, l.x); splitf(v.y, h.y, l.y);
  splitf(v.z, h.z, l.z); splitf(v.w, h.w, l.w);
  size_t o = (size_t)t * 65536 + (size_t)(c4 * 4) * 256 + r;
  outH[o] = h.x; outH[o + 256] = h.y; outH[o + 512] = h.z; outH[o + 768] = h.w;
  outL[o] = l.x; outL[o + 256] = l.y; outL[o + 512] = l.z; outL[o + 768] = l.w;
}

// ---------------------------------------------------------------------------
// Multi-slot LSTM cell kernel (unchanged from round 9).
// ---------------------------------------------------------------------------
struct CellSlot {
  const float* x;
  const float* wih;
  const float* whh;
  const float* bias;
  const float* hin;
  float* c;
  float* hout;
  float* hcopy;
  int hasx;
};
struct CellArgs { CellSlot s[3]; };

__global__ __launch_bounds__(256) void cell_multi(CellArgs args)
{
  const CellSlot S = args.s[blockIdx.x >> 8];
  const int inner = blockIdx.x & 255;
  const int jg = inner & 63, bg = inner >> 6;
  const int t = threadIdx.x;
  const int lane = t & 63;
  const int b = bg * 64 + lane;

  const int jw = __builtin_amdgcn_readfirstlane(jg * 4 + (t >> 6));
  const float4* wh = (const float4*)(S.whh + (size_t)jw * 1024);
  const float4* wi = (const float4*)(S.wih + (size_t)jw * 1024);
  const float* hcol = S.hin + b;
  float4 acc = *(const float4*)(S.bias + jw * 4);

  if (S.hasx) {
    const float* xcol = S.x + b;
#pragma unroll 8
    for (int k = 0; k < 256; ++k) {
      const float hv = hcol[k * 256];
      const float4 wv = wh[k];
      acc.x = fmaf(hv, wv.x, acc.x);
      acc.y = fmaf(hv, wv.y, acc.y);
      acc.z = fmaf(hv, wv.z, acc.z);
      acc.w = fmaf(hv, wv.w, acc.w);
      const float xv = xcol[k * 256];
      const float4 vv = wi[k];
      acc.x = fmaf(xv, vv.x, acc.x);
      acc.y = fmaf(xv, vv.y, acc.y);
      acc.z = fmaf(xv, vv.z, acc.z);
      acc.w = fmaf(xv, vv.w, acc.w);
    }
  } else {
#pragma unroll 8
    for (int k = 0; k < 256; ++k) {
      const float hv = hcol[k * 256];
      const float4 wv = wh[k];
      acc.x = fmaf(hv, wv.x, acc.x);
      acc.y = fmaf(hv, wv.y, acc.y);
      acc.z = fmaf(hv, wv.z, acc.z);
      acc.w = fmaf(hv, wv.w, acc.w);
    }
  }

  const int idx = jw * 256 + b;
  const float cold = S.c[idx];
  const float ig = sigf(acc.x), fg = sigf(acc.y);
  const float gg = tanhf(acc.z), og = sigf(acc.w);
  const float cn = fg * cold + ig * gg;
  const float hn = og * tanhf(cn);
  S.c[idx] = cn;
  S.hout[idx] = hn;
  if (S.hcopy) S.hcopy[idx] = hn;
}

// ---------------------------------------------------------------------------

extern "C" void kernel_launch(void* const* d_in, const int* in_sizes, int n_in,
                              void* d_out, int out_size, void* d_ws, size_t ws_size,
                              hipStream_t stream)
{
  const float* x_in  = (const float*)d_in[0];
  const float* w_en1 = (const float*)d_in[1];
  const float* b_en1 = (const float*)d_in[2];
  const float* w_en2 = (const float*)d_in[3];
  const float* b_en2 = (const float*)d_in[4];
  const float* cw[6][4];
  for (int i = 0; i < 6; ++i)
    for (int j = 0; j < 4; ++j) cw[i][j] = (const float*)d_in[5 + i * 4 + j];
  const float* w_de1 = (const float*)d_in[29];
  const float* b_de1 = (const float*)d_in[30];
  const float* w_de2 = (const float*)d_in[31];
  const float* b_de2 = (const float*)d_in[32];
  float* out = (float*)d_out;

  // ---- workspace layout (total ~87 MB) ----
  float* ws   = (float*)d_ws;
  float* wihP = ws;                        // 6 * 262144 f
  float* whhP = wihP + 6 * 262144;         // 6 * 262144 f
  float* bP   = whhP + 6 * 262144;         // 6 * 1024 f
  float* hb   = bP + 6 * 1024;             // 12 * 65536 f
  float* cb   = hb + 12 * 65536;           // 6 * 65536 f
  float* H3T  = cb + 6 * 65536;            // 10 * 65536 f
  float* z2   = H3T + 10 * 65536;          // 1,310,720 f
  float* z2T  = z2 + 1310720;              // 1,310,720 f
  unsigned short* us = (unsigned short*)(z2T + 1310720);
  unsigned short* WEN1H = us;              us += 4194304;
  unsigned short* WEN1L = us;              us += 4194304;
  unsigned short* WEN2H = us;              us += 262144;
  unsigned short* WEN2L = us;              us += 262144;
  unsigned short* WDE1H = us;              us += 262144;
  unsigned short* WDE1L = us;              us += 262144;
  unsigned short* WDE2H = us;              us += 4194304;
  unsigned short* WDE2L = us;              us += 4194304;
  unsigned short* Z1H   = us;              us += 5242880;
  unsigned short* Z1L   = us;              us += 5242880;
  // Y1/H3 alias the (dead-by-then) Z1 region:
  unsigned short* H3H = Z1H;
  unsigned short* H3L = Z1H + 655360;
  unsigned short* Y1H = Z1H + 1310720;
  unsigned short* Y1L = Z1H + 1310720 + 2621440;

  // ---- prep: cell packing, weight splits, state zero (every call) ----
  for (int i = 0; i < 6; ++i)
    prep_pack<<<256, 256, 0, stream>>>(cw[i][0], cw[i][1], cw[i][2], cw[i][3],
                                       wihP + i * 262144, whhP + i * 262144,
                                       bP + i * 1024);
  wsplit<<<4096, 256, 0, stream>>>(w_en1, WEN1H, WEN1L, 1048576);
  wsplit<<<256, 256, 0, stream>>>(w_en2, WEN2H, WEN2L, 65536);
  wsplit<<<256, 256, 0, stream>>>(w_de1, WDE1H, WDE1L, 65536);
  wsplit<<<4096, 256, 0, stream>>>(w_de2, WDE2H, WDE2L, 1048576);
  hipMemsetAsync(hb, 0, (size_t)18 * 65536 * sizeof(float), stream);

  // ---- encoder feedforward (all MFMA) ----
  gemm_sf<1><<<dim3(5120 / 128, 1024 / 64), 256, 0, stream>>>(
      x_in, WEN1H, WEN1L, b_en1, nullptr, Z1H, Z1L, 5120, 1024, 4096, 1);
  gemm_bb<0><<<dim3(5120 / 128, 256 / 64), 256, 0, stream>>>(
      Z1H, Z1L, WEN2H, WEN2L, b_en2, z2, nullptr, nullptr, 5120, 256, 1024, 1);
  transpose256<<<dim3(20, 64), 256, 0, stream>>>(z2, z2T);

  // ---- recurrence: layer-pipelined cell launches ----
  int pp[6] = {0, 0, 0, 0, 0, 0};
  auto HBuf = [&](int l, int p) { return hb + (size_t)(l * 2 + p) * 65536; };
  auto CBuf = [&](int l) { return cb + (size_t)l * 65536; };
  auto WI = [&](int l) { return wihP + (size_t)l * 262144; };
  auto WH = [&](int l) { return whhP + (size_t)l * 262144; };
  auto BB = [&](int l) { return bP + (size_t)l * 1024; };

  for (int s = 0; s <= 21; ++s) {
    CellArgs a; int n = 0; int tog[3]; int nt = 0;
    if (s < 20) {
      a.s[n++] = {z2T + (size_t)s * 65536, WI(0), WH(0), BB(0),
                  HBuf(0, pp[0]), CBuf(0), HBuf(0, pp[0] ^ 1), nullptr, 1};
      tog[nt++] = 0;
    }
    if (s >= 1 && s <= 20) {
      a.s[n++] = {HBuf(0, pp[0]), WI(1), WH(1), BB(1),
                  HBuf(1, pp[1]), CBuf(1), HBuf(1, pp[1] ^ 1), nullptr, 1};
      tog[nt++] = 1;
    }
    if (s >= 2) {
      a.s[n++] = {HBuf(1, pp[1]), WI(2), WH(2), BB(2),
                  HBuf(2, pp[2]), CBuf(2), HBuf(2, pp[2] ^ 1), nullptr, 1};
      tog[nt++] = 2;
    }
    cell_multi<<<n * 256, 256, 0, stream>>>(a);
    for (int i = 0; i < nt; ++i) pp[tog[i]] ^= 1;
  }

  for (int s = 0; s <= 11; ++s) {
    CellArgs a; int n = 0; int tog[3]; int nt = 0;
    if (s < 10) {
      const float* h1in = (s == 0) ? HBuf(2, pp[2]) : HBuf(3, pp[3]);
      a.s[n++] = {nullptr, WI(3), WH(3), BB(3),
                  h1in, CBuf(3), HBuf(3, pp[3] ^ 1), nullptr, 0};
      tog[nt++] = 3;
    }
    if (s >= 1 && s <= 10) {
      a.s[n++] = {HBuf(3, pp[3]), WI(4), WH(4), BB(4),
                  HBuf(4, pp[4]), CBuf(4), HBuf(4, pp[4] ^ 1), nullptr, 1};
      tog[nt++] = 4;
    }
    if (s >= 2) {
      a.s[n++] = {HBuf(4, pp[4]), WI(5), WH(5), BB(5),
                  HBuf(5, pp[5]), CBuf(5), HBuf(5, pp[5] ^ 1),
                  H3T + (size_t)(s - 2) * 65536, 1};
      tog[nt++] = 5;
    }
    cell_multi<<<n * 256, 256, 0, stream>>>(a);
    for (int i = 0; i < nt; ++i) pp[tog[i]] ^= 1;
  }

  // ---- decoder output FCs (all MFMA) ----
  transpose256s<<<dim3(10, 64), 256, 0, stream>>>(H3T, H3H, H3L);  // [s][j][b]->[s][b][j]
  gemm_bb<1><<<dim3(2560 / 128, 1024 / 64), 256, 0, stream>>>(
      H3H, H3L, WDE1H, WDE1L, b_de1, nullptr, Y1H, Y1L, 2560, 1024, 256, 1);
  gemm_bb<0><<<dim3(2560 / 128, 4096 / 64), 256, 0, stream>>>(
      Y1H, Y1L, WDE2H, WDE2L, b_de2, out, nullptr, nullptr, 2560, 4096, 1024, 2);

  (void)in_sizes; (void)n_in; (void)out_size; (void)ws_size;
}